// Round 1
// baseline (603.386 us; speedup 1.0000x reference)
//
#include <hip/hip_runtime.h>

// Problem constants (match reference file)
#define NPG     2048
#define KKEEP   1024
#define NNODES  131072
#define NEDGES  2097152
#define DFEAT   256
#define NGRAPH  64          // NNODES / NPG
#define NKEPT   (NGRAPH * KKEEP)   // 65536

// ---------------------------------------------------------------------------
// Pass 1: h[i] = dot(X[i,:], W[:,0])   (wave-per-row, float4 loads)
// ---------------------------------------------------------------------------
__global__ __launch_bounds__(256) void k_dot_rows(const float* __restrict__ X,
                                                  const float* __restrict__ W,
                                                  float* __restrict__ h) {
    const int wave = threadIdx.x >> 6;      // 0..3
    const int lane = threadIdx.x & 63;      // 0..63
    const int row  = blockIdx.x * 4 + wave; // grid sized exactly
    const float4 x = *reinterpret_cast<const float4*>(X + (size_t)row * DFEAT + lane * 4);
    const float4 w = *reinterpret_cast<const float4*>(W + lane * 4);
    float v = x.x * w.x + x.y * w.y + x.z * w.z + x.w * w.w;
    #pragma unroll
    for (int off = 32; off; off >>= 1) v += __shfl_down(v, off, 64);
    if (lane == 0) h[row] = v;
}

// ---------------------------------------------------------------------------
// Pass 2: in-degree count (self-loop added in dinv pass)
// ---------------------------------------------------------------------------
__global__ __launch_bounds__(256) void k_deg(const int* __restrict__ dst,
                                             int* __restrict__ deg) {
    for (int i = blockIdx.x * blockDim.x + threadIdx.x; i < NEDGES;
         i += gridDim.x * blockDim.x) {
        atomicAdd(&deg[dst[i]], 1);
    }
}

__global__ __launch_bounds__(256) void k_dinv(const int* __restrict__ deg,
                                              float* __restrict__ dinv) {
    const int i = blockIdx.x * blockDim.x + threadIdx.x;
    if (i < NNODES) dinv[i] = 1.0f / sqrtf((float)(deg[i] + 1)); // +1: self loop
}

// ---------------------------------------------------------------------------
// Pass 3: attn scatter over edges, then finalize with self-loop + bias
// ---------------------------------------------------------------------------
__global__ __launch_bounds__(256) void k_scatter(const int* __restrict__ src,
                                                 const int* __restrict__ dst,
                                                 const float* __restrict__ h,
                                                 const float* __restrict__ dinv,
                                                 float* __restrict__ attn) {
    for (int i = blockIdx.x * blockDim.x + threadIdx.x; i < NEDGES;
         i += gridDim.x * blockDim.x) {
        const int s = src[i];
        const int d = dst[i];
        atomicAdd(&attn[d], h[s] * dinv[s] * dinv[d]);
    }
}

__global__ __launch_bounds__(256) void k_finalize(const float* __restrict__ h,
                                                  const float* __restrict__ dinv,
                                                  const float* __restrict__ b,
                                                  float* __restrict__ attn) {
    const int i = blockIdx.x * blockDim.x + threadIdx.x;
    if (i < NNODES) {
        const float di = dinv[i];
        attn[i] += h[i] * di * di + b[0];
    }
}

// ---------------------------------------------------------------------------
// Pass 4: exact top-k by rank. rank(i) = #{j: s_j>s_i} + #{j: s_j==s_i, j<i}
// Reproduces jax.lax.top_k descending order with index tie-break.
// One block per graph; scores staged in LDS (8 KB); 2 nodes per thread.
// ---------------------------------------------------------------------------
__global__ __launch_bounds__(1024) void k_topk(const float* __restrict__ attn,
                                               int* __restrict__ perm,
                                               int* __restrict__ newid) {
    __shared__ float s[NPG];
    const int g = blockIdx.x;
    const float* a = attn + (size_t)g * NPG;
    for (int i = threadIdx.x; i < NPG; i += blockDim.x) s[i] = a[i];
    __syncthreads();

    const int i0 = threadIdx.x;
    const int i1 = threadIdx.x + 1024;
    const float s0 = s[i0];
    const float s1 = s[i1];
    int c0 = 0, c1 = 0;
    for (int j = 0; j < NPG; ++j) {
        const float sj = s[j];          // LDS broadcast (all lanes same addr)
        c0 += (sj > s0) || (sj == s0 && j < i0);
        c1 += (sj > s1) || (sj == s1 && j < i1);
    }
    const int node0 = g * NPG + i0;
    const int node1 = g * NPG + i1;
    if (c0 < KKEEP) { const int id = g * KKEEP + c0; perm[id] = node0; newid[node0] = id; }
    else            { newid[node0] = -1; }
    if (c1 < KKEEP) { const int id = g * KKEEP + c1; perm[id] = node1; newid[node1] = id; }
    else            { newid[node1] = -1; }
}

// ---------------------------------------------------------------------------
// Pass 5: gather kept rows, gate by tanh(score); write graph indicator
// ---------------------------------------------------------------------------
__global__ __launch_bounds__(256) void k_gather(const float* __restrict__ X,
                                                const float* __restrict__ attn,
                                                const int* __restrict__ perm,
                                                const int* __restrict__ gi_in,
                                                float* __restrict__ out_x,
                                                float* __restrict__ out_gi) {
    const int wave = threadIdx.x >> 6;
    const int lane = threadIdx.x & 63;
    const int row  = blockIdx.x * 4 + wave;   // 0..NKEPT-1, grid sized exactly
    const int node = perm[row];
    const float gate = tanhf(attn[node]);
    const float4 x = *reinterpret_cast<const float4*>(X + (size_t)node * DFEAT + lane * 4);
    float4 o;
    o.x = x.x * gate; o.y = x.y * gate; o.z = x.z * gate; o.w = x.w * gate;
    *reinterpret_cast<float4*>(out_x + (size_t)row * DFEAT + lane * 4) = o;
    if (lane == 0 && wave == 0) {
        // one write per row handled by wave 0 lane 0 of each row's wave:
    }
    if (lane == 0) out_gi[row] = (float)gi_in[node];
}

// ---------------------------------------------------------------------------
// Pass 6: edge remap; dropped edges -> -1 (both endpoints must be kept)
// ---------------------------------------------------------------------------
__global__ __launch_bounds__(256) void k_edges(const int* __restrict__ src,
                                               const int* __restrict__ dst,
                                               const int* __restrict__ newid,
                                               float* __restrict__ out_src,
                                               float* __restrict__ out_dst) {
    for (int i = blockIdx.x * blockDim.x + threadIdx.x; i < NEDGES;
         i += gridDim.x * blockDim.x) {
        const int ns = newid[src[i]];
        const int nd = newid[dst[i]];
        const bool ok = (ns >= 0) && (nd >= 0);
        out_src[i] = ok ? (float)ns : -1.0f;
        out_dst[i] = ok ? (float)nd : -1.0f;
    }
}

// ---------------------------------------------------------------------------
extern "C" void kernel_launch(void* const* d_in, const int* in_sizes, int n_in,
                              void* d_out, int out_size, void* d_ws, size_t ws_size,
                              hipStream_t stream) {
    const float* X    = (const float*)d_in[0];           // [N, 256]
    const int*   gi   = (const int*)d_in[1];             // [N]
    const int*   ei   = (const int*)d_in[2];             // [2, E]
    const float* W    = (const float*)d_in[3];           // [256, 1]
    const float* b    = (const float*)d_in[4];           // [1]
    const int* src = ei;
    const int* dst = ei + NEDGES;

    // Workspace layout (bytes)
    char* ws = (char*)d_ws;
    int*   deg   = (int*)  (ws + 0);                     // N ints
    float* attn  = (float*)(ws + 1 * NNODES * 4);        // N floats  (zeroed with deg)
    float* h     = (float*)(ws + 2 * NNODES * 4);        // N floats
    float* dinv  = (float*)(ws + 3 * NNODES * 4);        // N floats
    int*   newid = (int*)  (ws + 4 * NNODES * 4);        // N ints
    int*   perm  = (int*)  (ws + 5 * NNODES * 4);        // NKEPT ints

    // Output layout (all float32 values in one flat buffer)
    float* out_x   = (float*)d_out;                      // NKEPT*256
    float* out_src = out_x + (size_t)NKEPT * DFEAT;      // E
    float* out_dst = out_src + NEDGES;                   // E
    float* out_gi  = out_dst + NEDGES;                   // NKEPT

    // Zero deg + attn (ws is poisoned to 0xAA before every launch)
    hipMemsetAsync(d_ws, 0, (size_t)2 * NNODES * 4, stream);

    k_dot_rows<<<NNODES / 4, 256, 0, stream>>>(X, W, h);
    k_deg<<<2048, 256, 0, stream>>>(dst, deg);
    k_dinv<<<NNODES / 256, 256, 0, stream>>>(deg, dinv);
    k_scatter<<<2048, 256, 0, stream>>>(src, dst, h, dinv, attn);
    k_finalize<<<NNODES / 256, 256, 0, stream>>>(h, dinv, b, attn);
    k_topk<<<NGRAPH, 1024, 0, stream>>>(attn, perm, newid);
    k_gather<<<NKEPT / 4, 256, 0, stream>>>(X, attn, perm, gi, out_x, out_gi);
    k_edges<<<2048, 256, 0, stream>>>(src, dst, newid, out_src, out_dst);
}

// Round 2
// 523.672 us; speedup vs baseline: 1.1522x; 1.1522x over previous
//
#include <hip/hip_runtime.h>

// Problem constants (match reference file)
#define NPG     2048
#define KKEEP   1024
#define NNODES  131072
#define NEDGES  2097152
#define DFEAT   256
#define NGRAPH  64                 // NNODES / NPG
#define NKEPT   (NGRAPH * KKEEP)   // 65536

// ---------------------------------------------------------------------------
// Pass 1: h[i] = dot(X[i,:], W[:,0])   (wave-per-row, float4 loads)
// ---------------------------------------------------------------------------
__global__ __launch_bounds__(256) void k_dot_rows(const float* __restrict__ X,
                                                  const float* __restrict__ W,
                                                  float* __restrict__ h) {
    const int wave = threadIdx.x >> 6;      // 0..3
    const int lane = threadIdx.x & 63;      // 0..63
    const int row  = blockIdx.x * 4 + wave; // grid sized exactly
    const float4 x = *reinterpret_cast<const float4*>(X + (size_t)row * DFEAT + lane * 4);
    const float4 w = *reinterpret_cast<const float4*>(W + lane * 4);
    float v = x.x * w.x + x.y * w.y + x.z * w.z + x.w * w.w;
    #pragma unroll
    for (int off = 32; off; off >>= 1) v += __shfl_down(v, off, 64);
    if (lane == 0) h[row] = v;
}

// ---------------------------------------------------------------------------
// Pass 2: in-degree count (self-loop added analytically later). int4 loads.
// ---------------------------------------------------------------------------
__global__ __launch_bounds__(256) void k_deg(const int* __restrict__ dst,
                                             int* __restrict__ deg) {
    const int i = blockIdx.x * blockDim.x + threadIdx.x;   // grid covers E/4 exactly
    const int4 d = reinterpret_cast<const int4*>(dst)[i];
    atomicAdd(&deg[d.x], 1);
    atomicAdd(&deg[d.y], 1);
    atomicAdd(&deg[d.z], 1);
    atomicAdd(&deg[d.w], 1);
}

// dinv = (deg+1)^-0.5 ; g = h * dinv  (source-side weight, gathered per edge)
__global__ __launch_bounds__(256) void k_prep(const int* __restrict__ deg,
                                              const float* __restrict__ h,
                                              float* __restrict__ dinv,
                                              float* __restrict__ g) {
    const int i = blockIdx.x * blockDim.x + threadIdx.x;
    const float di = 1.0f / sqrtf((float)(deg[i] + 1)); // +1: self loop
    dinv[i] = di;
    g[i] = h[i] * di;
}

// ---------------------------------------------------------------------------
// Pass 3: attn[d] += g[s] over edges (dinv[d] factored out -> finalize)
// ---------------------------------------------------------------------------
__global__ __launch_bounds__(256) void k_scatter(const int* __restrict__ src,
                                                 const int* __restrict__ dst,
                                                 const float* __restrict__ g,
                                                 float* __restrict__ attn) {
    const int i = blockIdx.x * blockDim.x + threadIdx.x;   // grid covers E/4 exactly
    const int4 s = reinterpret_cast<const int4*>(src)[i];
    const int4 d = reinterpret_cast<const int4*>(dst)[i];
    atomicAdd(&attn[d.x], g[s.x]);
    atomicAdd(&attn[d.y], g[s.y]);
    atomicAdd(&attn[d.z], g[s.z]);
    atomicAdd(&attn[d.w], g[s.w]);
}

// final score = (edge_sum + g[i]) * dinv[i] + b     (g[i]*dinv[i] = self-loop)
__global__ __launch_bounds__(256) void k_finalize(const float* __restrict__ g,
                                                  const float* __restrict__ dinv,
                                                  const float* __restrict__ b,
                                                  float* __restrict__ attn) {
    const int i = blockIdx.x * blockDim.x + threadIdx.x;
    attn[i] = (attn[i] + g[i]) * dinv[i] + b[0];
}

// ---------------------------------------------------------------------------
// Pass 4: exact top-k by rank. rank(i) = #{j: s_j>s_i} + #{j: s_j==s_i, j<i}
// Reproduces jax.lax.top_k descending order with index tie-break.
// 4 blocks per graph x 256 threads; 2 nodes/thread; float4 LDS broadcasts.
// ---------------------------------------------------------------------------
__global__ __launch_bounds__(256) void k_topk(const float* __restrict__ attn,
                                              int* __restrict__ perm,
                                              int* __restrict__ newid) {
    __shared__ float s[NPG];
    const int g   = blockIdx.x >> 2;       // graph
    const int sub = blockIdx.x & 3;        // which 512-node slice
    const float* a = attn + (size_t)g * NPG;
    for (int i = threadIdx.x; i < NPG / 4; i += 256)
        reinterpret_cast<float4*>(s)[i] = reinterpret_cast<const float4*>(a)[i];
    __syncthreads();

    const int i0 = sub * 512 + threadIdx.x;
    const int i1 = i0 + 256;
    const float s0 = s[i0];
    const float s1 = s[i1];
    int c0 = 0, c1 = 0;
    const float4* s4 = reinterpret_cast<const float4*>(s);
    #pragma unroll 8
    for (int j4 = 0; j4 < NPG / 4; ++j4) {
        const float4 v = s4[j4];           // broadcast read, conflict-free
        const int jb = j4 * 4;
        c0 += (int)(v.x > s0) + (int)(v.y > s0) + (int)(v.z > s0) + (int)(v.w > s0);
        c0 += (int)((v.x == s0) && (jb + 0 < i0)) + (int)((v.y == s0) && (jb + 1 < i0))
            + (int)((v.z == s0) && (jb + 2 < i0)) + (int)((v.w == s0) && (jb + 3 < i0));
        c1 += (int)(v.x > s1) + (int)(v.y > s1) + (int)(v.z > s1) + (int)(v.w > s1);
        c1 += (int)((v.x == s1) && (jb + 0 < i1)) + (int)((v.y == s1) && (jb + 1 < i1))
            + (int)((v.z == s1) && (jb + 2 < i1)) + (int)((v.w == s1) && (jb + 3 < i1));
    }
    const int node0 = g * NPG + i0;
    const int node1 = g * NPG + i1;
    if (c0 < KKEEP) { const int id = g * KKEEP + c0; perm[id] = node0; newid[node0] = id; }
    else            { newid[node0] = -1; }
    if (c1 < KKEEP) { const int id = g * KKEEP + c1; perm[id] = node1; newid[node1] = id; }
    else            { newid[node1] = -1; }
}

// ---------------------------------------------------------------------------
// Pass 5: gather kept rows, gate by tanh(score); graph indicator = row/K
// ---------------------------------------------------------------------------
__global__ __launch_bounds__(256) void k_gather(const float* __restrict__ X,
                                                const float* __restrict__ attn,
                                                const int* __restrict__ perm,
                                                float* __restrict__ out_x,
                                                float* __restrict__ out_gi) {
    const int wave = threadIdx.x >> 6;
    const int lane = threadIdx.x & 63;
    const int row  = blockIdx.x * 4 + wave;   // grid sized exactly (NKEPT/4)
    const int node = perm[row];
    const float gate = tanhf(attn[node]);
    const float4 x = *reinterpret_cast<const float4*>(X + (size_t)node * DFEAT + lane * 4);
    float4 o;
    o.x = x.x * gate; o.y = x.y * gate; o.z = x.z * gate; o.w = x.w * gate;
    *reinterpret_cast<float4*>(out_x + (size_t)row * DFEAT + lane * 4) = o;
    if (lane == 0) out_gi[row] = (float)(row >> 10);   // row / KKEEP = graph id
}

// ---------------------------------------------------------------------------
// Pass 6: edge remap; dropped edges -> -1 (both endpoints must be kept)
// ---------------------------------------------------------------------------
__global__ __launch_bounds__(256) void k_edges(const int* __restrict__ src,
                                               const int* __restrict__ dst,
                                               const int* __restrict__ newid,
                                               float* __restrict__ out_src,
                                               float* __restrict__ out_dst) {
    const int i = blockIdx.x * blockDim.x + threadIdx.x;   // grid covers E/4 exactly
    const int4 s = reinterpret_cast<const int4*>(src)[i];
    const int4 d = reinterpret_cast<const int4*>(dst)[i];
    const int ns0 = newid[s.x], nd0 = newid[d.x];
    const int ns1 = newid[s.y], nd1 = newid[d.y];
    const int ns2 = newid[s.z], nd2 = newid[d.z];
    const int ns3 = newid[s.w], nd3 = newid[d.w];
    float4 os, od;
    os.x = (ns0 >= 0 && nd0 >= 0) ? (float)ns0 : -1.0f;
    od.x = (ns0 >= 0 && nd0 >= 0) ? (float)nd0 : -1.0f;
    os.y = (ns1 >= 0 && nd1 >= 0) ? (float)ns1 : -1.0f;
    od.y = (ns1 >= 0 && nd1 >= 0) ? (float)nd1 : -1.0f;
    os.z = (ns2 >= 0 && nd2 >= 0) ? (float)ns2 : -1.0f;
    od.z = (ns2 >= 0 && nd2 >= 0) ? (float)nd2 : -1.0f;
    os.w = (ns3 >= 0 && nd3 >= 0) ? (float)ns3 : -1.0f;
    od.w = (ns3 >= 0 && nd3 >= 0) ? (float)nd3 : -1.0f;
    reinterpret_cast<float4*>(out_src)[i] = os;
    reinterpret_cast<float4*>(out_dst)[i] = od;
}

// ---------------------------------------------------------------------------
extern "C" void kernel_launch(void* const* d_in, const int* in_sizes, int n_in,
                              void* d_out, int out_size, void* d_ws, size_t ws_size,
                              hipStream_t stream) {
    const float* X    = (const float*)d_in[0];           // [N, 256]
    const int*   ei   = (const int*)d_in[2];             // [2, E]
    const float* W    = (const float*)d_in[3];           // [256, 1]
    const float* b    = (const float*)d_in[4];           // [1]
    const int* src = ei;
    const int* dst = ei + NEDGES;

    // Workspace layout
    char* ws = (char*)d_ws;
    int*   deg   = (int*)  (ws + 0);                     // N ints   (zeroed)
    float* attn  = (float*)(ws + 1 * (size_t)NNODES * 4);// N floats (zeroed)
    float* h     = (float*)(ws + 2 * (size_t)NNODES * 4);// N floats
    float* dinv  = (float*)(ws + 3 * (size_t)NNODES * 4);// N floats
    float* gg    = (float*)(ws + 4 * (size_t)NNODES * 4);// N floats
    int*   newid = (int*)  (ws + 5 * (size_t)NNODES * 4);// N ints
    int*   perm  = (int*)  (ws + 6 * (size_t)NNODES * 4);// NKEPT ints

    // Output layout (all float32 values in one flat buffer)
    float* out_x   = (float*)d_out;                      // NKEPT*256
    float* out_src = out_x + (size_t)NKEPT * DFEAT;      // E
    float* out_dst = out_src + NEDGES;                   // E
    float* out_gi  = out_dst + NEDGES;                   // NKEPT

    // Zero deg + attn (ws is poisoned to 0xAA before every launch)
    hipMemsetAsync(d_ws, 0, (size_t)2 * NNODES * 4, stream);

    k_dot_rows<<<NNODES / 4, 256, 0, stream>>>(X, W, h);
    k_deg     <<<NEDGES / 4 / 256, 256, 0, stream>>>(dst, deg);
    k_prep    <<<NNODES / 256, 256, 0, stream>>>(deg, h, dinv, gg);
    k_scatter <<<NEDGES / 4 / 256, 256, 0, stream>>>(src, dst, gg, attn);
    k_finalize<<<NNODES / 256, 256, 0, stream>>>(gg, dinv, b, attn);
    k_topk    <<<NGRAPH * 4, 256, 0, stream>>>(attn, perm, newid);
    k_gather  <<<NKEPT / 4, 256, 0, stream>>>(X, attn, perm, out_x, out_gi);
    k_edges   <<<NEDGES / 4 / 256, 256, 0, stream>>>(src, dst, newid, out_src, out_dst);
}

// Round 4
// 396.162 us; speedup vs baseline: 1.5231x; 1.3219x over previous
//
#include <hip/hip_runtime.h>

// Problem constants (match reference file)
#define NPG     2048
#define KKEEP   1024
#define NNODES  131072
#define NEDGES  2097152
#define DFEAT   256
#define NGRAPH  64                 // NNODES / NPG
#define NKEPT   (NGRAPH * KKEEP)   // 65536

// Binning constants
#define NBLK    256                // edge slices (= threads per bucket-pass block)
#define SLICE   (NEDGES / NBLK)    // 8192 edges per slice
#define NBUCK   1024               // dst buckets (dst >> 7)
#define BNODES  (NNODES / NBUCK)   // 128 nodes per bucket

// ---------------------------------------------------------------------------
// Pass 1: h[i] = dot(X[i,:], W[:,0])   (wave-per-row, float4 loads)
// ---------------------------------------------------------------------------
__global__ __launch_bounds__(256) void k_dot_rows(const float* __restrict__ X,
                                                  const float* __restrict__ W,
                                                  float* __restrict__ h) {
    const int wave = threadIdx.x >> 6;
    const int lane = threadIdx.x & 63;
    const int row  = blockIdx.x * 4 + wave;
    const float4 x = *reinterpret_cast<const float4*>(X + (size_t)row * DFEAT + lane * 4);
    const float4 w = *reinterpret_cast<const float4*>(W + lane * 4);
    float v = x.x * w.x + x.y * w.y + x.z * w.z + x.w * w.w;
    #pragma unroll
    for (int off = 32; off; off >>= 1) v += __shfl_down(v, off, 64);
    if (lane == 0) h[row] = v;
}

// ---------------------------------------------------------------------------
// Pass 2: block-local counting sort of edges by dst bucket.
// Block blk owns edges [blk*SLICE, (blk+1)*SLICE). Output: codes[] in
// block-contiguous, bucket-sorted order; base[blk][bucket] = exclusive
// start of (blk,bucket) segment within the block's region.
// code = (dst&127)<<17 | src   (17+7 = 24 bits)
// All atomics are LDS; global writes fully coalesced.
// ---------------------------------------------------------------------------
__global__ __launch_bounds__(256) void k_binsort(const int* __restrict__ src,
                                                 const int* __restrict__ dst,
                                                 int* __restrict__ codes,
                                                 int* __restrict__ base) {
    __shared__ int hist[NBUCK];     // histogram, then running offsets
    __shared__ int scan[256];
    __shared__ int lcode[SLICE];    // 32 KB staging
    const int blk = blockIdx.x;
    const int t   = threadIdx.x;

    for (int i = t; i < NBUCK; i += 256) hist[i] = 0;
    __syncthreads();

    const int4* d4 = reinterpret_cast<const int4*>(dst) + blk * (SLICE / 4);
    const int4* s4 = reinterpret_cast<const int4*>(src) + blk * (SLICE / 4);

    // loop 1: bucket histogram
    for (int k = t; k < SLICE / 4; k += 256) {
        const int4 d = d4[k];
        atomicAdd(&hist[d.x >> 7], 1);
        atomicAdd(&hist[d.y >> 7], 1);
        atomicAdd(&hist[d.z >> 7], 1);
        atomicAdd(&hist[d.w >> 7], 1);
    }
    __syncthreads();

    // exclusive prefix over 1024 bins (4 bins per thread + block scan)
    const int v0 = hist[4 * t], v1 = hist[4 * t + 1],
              v2 = hist[4 * t + 2], v3 = hist[4 * t + 3];
    const int tsum = v0 + v1 + v2 + v3;
    scan[t] = tsum;
    __syncthreads();
    for (int off = 1; off < 256; off <<= 1) {
        const int x = (t >= off) ? scan[t - off] : 0;
        __syncthreads();
        scan[t] += x;
        __syncthreads();
    }
    const int excl = scan[t] - tsum;            // exclusive prefix of thread sums
    const int e0 = excl, e1 = e0 + v0, e2 = e1 + v1, e3 = e2 + v2;
    hist[4 * t]     = e0;
    hist[4 * t + 1] = e1;
    hist[4 * t + 2] = e2;
    hist[4 * t + 3] = e3;
    int4 eb; eb.x = e0; eb.y = e1; eb.z = e2; eb.w = e3;
    reinterpret_cast<int4*>(base + (size_t)blk * NBUCK)[t] = eb;   // coalesced
    __syncthreads();

    // loop 2: scatter codes into LDS at reserved positions
    for (int k = t; k < SLICE / 4; k += 256) {
        const int4 d = d4[k];
        const int4 s = s4[k];
        int p;
        p = atomicAdd(&hist[d.x >> 7], 1); lcode[p] = ((d.x & 127) << 17) | s.x;
        p = atomicAdd(&hist[d.y >> 7], 1); lcode[p] = ((d.y & 127) << 17) | s.y;
        p = atomicAdd(&hist[d.z >> 7], 1); lcode[p] = ((d.z & 127) << 17) | s.z;
        p = atomicAdd(&hist[d.w >> 7], 1); lcode[p] = ((d.w & 127) << 17) | s.w;
    }
    __syncthreads();

    // stream out, coalesced
    int4* out4 = reinterpret_cast<int4*>(codes) + blk * (SLICE / 4);
    for (int k = t; k < SLICE / 4; k += 256)
        out4[k] = reinterpret_cast<const int4*>(lcode)[k];
}

// ---------------------------------------------------------------------------
// Pass 3: in-degree per node from sorted codes (LDS accumulate, 1 blk/bucket)
// thread t walks segment (slice t, bucket blockIdx.x)
// ---------------------------------------------------------------------------
__global__ __launch_bounds__(256) void k_deg2(const int* __restrict__ codes,
                                              const int* __restrict__ base,
                                              int* __restrict__ deg) {
    __shared__ int acc[BNODES];
    const int b = blockIdx.x;
    const int t = threadIdx.x;
    if (t < BNODES) acc[t] = 0;
    __syncthreads();
    const int s0 = base[(size_t)t * NBUCK + b];
    const int s1 = (b == NBUCK - 1) ? SLICE : base[(size_t)t * NBUCK + b + 1];
    const int* c = codes + (size_t)t * SLICE;
    for (int k = s0; k < s1; ++k) atomicAdd(&acc[c[k] >> 17], 1);
    __syncthreads();
    if (t < BNODES) deg[b * BNODES + t] = acc[t];
}

// dinv = (deg+1)^-0.5 ; g = h * dinv  (source-side weight)
__global__ __launch_bounds__(256) void k_prep(const int* __restrict__ deg,
                                              const float* __restrict__ h,
                                              float* __restrict__ dinv,
                                              float* __restrict__ g) {
    const int i = blockIdx.x * blockDim.x + threadIdx.x;
    const float di = 1.0f / sqrtf((float)(deg[i] + 1)); // +1: self loop
    dinv[i] = di;
    g[i] = h[i] * di;
}

// ---------------------------------------------------------------------------
// Pass 4: attn accumulate (LDS) + fused finalize.
// attn[n] = (sum_{edges s->n} g[s] + g[n]) * dinv[n] + bias
// ---------------------------------------------------------------------------
__global__ __launch_bounds__(256) void k_attn(const int* __restrict__ codes,
                                              const int* __restrict__ base,
                                              const float* __restrict__ g,
                                              const float* __restrict__ dinv,
                                              const float* __restrict__ bias,
                                              float* __restrict__ attn) {
    __shared__ float acc[BNODES];
    const int b = blockIdx.x;
    const int t = threadIdx.x;
    if (t < BNODES) acc[t] = 0.0f;
    __syncthreads();
    const int s0 = base[(size_t)t * NBUCK + b];
    const int s1 = (b == NBUCK - 1) ? SLICE : base[(size_t)t * NBUCK + b + 1];
    const int* c = codes + (size_t)t * SLICE;
    for (int k = s0; k < s1; ++k) {
        const int code = c[k];
        atomicAdd(&acc[code >> 17], g[code & 0x1FFFF]);
    }
    __syncthreads();
    if (t < BNODES) {
        const int node = b * BNODES + t;
        attn[node] = (acc[t] + g[node]) * dinv[node] + bias[0];
    }
}

// ---------------------------------------------------------------------------
// Pass 5: exact top-k by rank (4 blocks/graph, 2 nodes/thread, float4 LDS)
// ---------------------------------------------------------------------------
__global__ __launch_bounds__(256) void k_topk(const float* __restrict__ attn,
                                              int* __restrict__ perm,
                                              int* __restrict__ newid) {
    __shared__ float s[NPG];
    const int g   = blockIdx.x >> 2;
    const int sub = blockIdx.x & 3;
    const float* a = attn + (size_t)g * NPG;
    for (int i = threadIdx.x; i < NPG / 4; i += 256)
        reinterpret_cast<float4*>(s)[i] = reinterpret_cast<const float4*>(a)[i];
    __syncthreads();

    const int i0 = sub * 512 + threadIdx.x;
    const int i1 = i0 + 256;
    const float s0 = s[i0];
    const float s1 = s[i1];
    int c0 = 0, c1 = 0;
    const float4* s4 = reinterpret_cast<const float4*>(s);
    #pragma unroll 8
    for (int j4 = 0; j4 < NPG / 4; ++j4) {
        const float4 v = s4[j4];
        const int jb = j4 * 4;
        c0 += (int)(v.x > s0) + (int)(v.y > s0) + (int)(v.z > s0) + (int)(v.w > s0);
        c0 += (int)((v.x == s0) && (jb + 0 < i0)) + (int)((v.y == s0) && (jb + 1 < i0))
            + (int)((v.z == s0) && (jb + 2 < i0)) + (int)((v.w == s0) && (jb + 3 < i0));
        c1 += (int)(v.x > s1) + (int)(v.y > s1) + (int)(v.z > s1) + (int)(v.w > s1);
        c1 += (int)((v.x == s1) && (jb + 0 < i1)) + (int)((v.y == s1) && (jb + 1 < i1))
            + (int)((v.z == s1) && (jb + 2 < i1)) + (int)((v.w == s1) && (jb + 3 < i1));
    }
    const int node0 = g * NPG + i0;
    const int node1 = g * NPG + i1;
    if (c0 < KKEEP) { const int id = g * KKEEP + c0; perm[id] = node0; newid[node0] = id; }
    else            { newid[node0] = -1; }
    if (c1 < KKEEP) { const int id = g * KKEEP + c1; perm[id] = node1; newid[node1] = id; }
    else            { newid[node1] = -1; }
}

// ---------------------------------------------------------------------------
// Pass 6: gather kept rows, gate by tanh(score); graph indicator = row/K
// ---------------------------------------------------------------------------
__global__ __launch_bounds__(256) void k_gather(const float* __restrict__ X,
                                                const float* __restrict__ attn,
                                                const int* __restrict__ perm,
                                                float* __restrict__ out_x,
                                                float* __restrict__ out_gi) {
    const int wave = threadIdx.x >> 6;
    const int lane = threadIdx.x & 63;
    const int row  = blockIdx.x * 4 + wave;
    const int node = perm[row];
    const float gate = tanhf(attn[node]);
    const float4 x = *reinterpret_cast<const float4*>(X + (size_t)node * DFEAT + lane * 4);
    float4 o;
    o.x = x.x * gate; o.y = x.y * gate; o.z = x.z * gate; o.w = x.w * gate;
    *reinterpret_cast<float4*>(out_x + (size_t)row * DFEAT + lane * 4) = o;
    if (lane == 0) out_gi[row] = (float)(row >> 10);   // row / KKEEP
}

// ---------------------------------------------------------------------------
// Pass 7: edge remap; dropped edges -> -1
// ---------------------------------------------------------------------------
__global__ __launch_bounds__(256) void k_edges(const int* __restrict__ src,
                                               const int* __restrict__ dst,
                                               const int* __restrict__ newid,
                                               float* __restrict__ out_src,
                                               float* __restrict__ out_dst) {
    const int i = blockIdx.x * blockDim.x + threadIdx.x;
    const int4 s = reinterpret_cast<const int4*>(src)[i];
    const int4 d = reinterpret_cast<const int4*>(dst)[i];
    const int ns0 = newid[s.x], nd0 = newid[d.x];
    const int ns1 = newid[s.y], nd1 = newid[d.y];
    const int ns2 = newid[s.z], nd2 = newid[d.z];
    const int ns3 = newid[s.w], nd3 = newid[d.w];
    float4 os, od;
    os.x = (ns0 >= 0 && nd0 >= 0) ? (float)ns0 : -1.0f;
    od.x = (ns0 >= 0 && nd0 >= 0) ? (float)nd0 : -1.0f;
    os.y = (ns1 >= 0 && nd1 >= 0) ? (float)ns1 : -1.0f;
    od.y = (ns1 >= 0 && nd1 >= 0) ? (float)nd1 : -1.0f;
    os.z = (ns2 >= 0 && nd2 >= 0) ? (float)ns2 : -1.0f;
    od.z = (ns2 >= 0 && nd2 >= 0) ? (float)nd2 : -1.0f;
    os.w = (ns3 >= 0 && nd3 >= 0) ? (float)ns3 : -1.0f;
    od.w = (ns3 >= 0 && nd3 >= 0) ? (float)nd3 : -1.0f;
    reinterpret_cast<float4*>(out_src)[i] = os;
    reinterpret_cast<float4*>(out_dst)[i] = od;
}

// ---------------------------------------------------------------------------
extern "C" void kernel_launch(void* const* d_in, const int* in_sizes, int n_in,
                              void* d_out, int out_size, void* d_ws, size_t ws_size,
                              hipStream_t stream) {
    const float* X  = (const float*)d_in[0];             // [N, 256]
    const int*   ei = (const int*)d_in[2];               // [2, E]
    const float* W  = (const float*)d_in[3];             // [256, 1]
    const float* b  = (const float*)d_in[4];             // [1]
    const int* src = ei;
    const int* dst = ei + NEDGES;

    // Workspace layout (everything fully written before read; no zeroing)
    char* ws = (char*)d_ws;
    int*   deg   = (int*)  (ws + 0 * (size_t)NNODES * 4);
    float* attn  = (float*)(ws + 1 * (size_t)NNODES * 4);
    float* h     = (float*)(ws + 2 * (size_t)NNODES * 4);
    float* dinv  = (float*)(ws + 3 * (size_t)NNODES * 4);
    float* gg    = (float*)(ws + 4 * (size_t)NNODES * 4);
    int*   newid = (int*)  (ws + 5 * (size_t)NNODES * 4);
    int*   perm  = (int*)  (ws + 6 * (size_t)NNODES * 4);

    // Output layout (all float32 values in one flat buffer)
    float* out_x   = (float*)d_out;                      // NKEPT*256
    float* out_src = out_x + (size_t)NKEPT * DFEAT;      // E
    float* out_dst = out_src + NEDGES;                   // E
    float* out_gi  = out_dst + NEDGES;                   // NKEPT

    // Scratch for binning lives in the edge-output slots: codes (8 MB) and
    // base (1 MB) are consumed by k_deg2/k_attn, long before k_edges
    // overwrites these regions with the final edge outputs.
    int* codes = (int*)out_src;                          // NEDGES ints
    int* base  = (int*)out_dst;                          // NBLK*NBUCK ints

    k_dot_rows<<<NNODES / 4, 256, 0, stream>>>(X, W, h);
    k_binsort <<<NBLK, 256, 0, stream>>>(src, dst, codes, base);
    k_deg2    <<<NBUCK, 256, 0, stream>>>(codes, base, deg);
    k_prep    <<<NNODES / 256, 256, 0, stream>>>(deg, h, dinv, gg);
    k_attn    <<<NBUCK, 256, 0, stream>>>(codes, base, gg, dinv, b, attn);
    k_topk    <<<NGRAPH * 4, 256, 0, stream>>>(attn, perm, newid);
    k_gather  <<<NKEPT / 4, 256, 0, stream>>>(X, attn, perm, out_x, out_gi);
    k_edges   <<<NEDGES / 4 / 256, 256, 0, stream>>>(src, dst, newid, out_src, out_dst);
}

// Round 6
// 342.683 us; speedup vs baseline: 1.7608x; 1.1561x over previous
//
#include <hip/hip_runtime.h>

// Problem constants (match reference file)
#define NPG     2048
#define KKEEP   1024
#define NNODES  131072
#define NEDGES  2097152
#define DFEAT   256
#define NGRAPH  64                 // NNODES / NPG
#define NKEPT   (NGRAPH * KKEEP)   // 65536

// Binning constants
#define NBLK    256                // edge slices (= threads per bucket-pass block)
#define SLICE   (NEDGES / NBLK)    // 8192 edges per slice
#define NBUCK   1024               // dst buckets (dst >> 7)
#define BNODES  (NNODES / NBUCK)   // 128 nodes per bucket

// ---------------------------------------------------------------------------
// Pass 1: h[i] = dot(X[i,:], W[:,0])   (wave-per-row, float4 loads)
// ---------------------------------------------------------------------------
__global__ __launch_bounds__(256) void k_dot_rows(const float* __restrict__ X,
                                                  const float* __restrict__ W,
                                                  float* __restrict__ h) {
    const int wave = threadIdx.x >> 6;
    const int lane = threadIdx.x & 63;
    const int row  = blockIdx.x * 4 + wave;
    const float4 x = *reinterpret_cast<const float4*>(X + (size_t)row * DFEAT + lane * 4);
    const float4 w = *reinterpret_cast<const float4*>(W + lane * 4);
    float v = x.x * w.x + x.y * w.y + x.z * w.z + x.w * w.w;
    #pragma unroll
    for (int off = 32; off; off >>= 1) v += __shfl_down(v, off, 64);
    if (lane == 0) h[row] = v;
}

// ---------------------------------------------------------------------------
// Pass 2: block-local counting sort of edges by dst bucket.
// code = (dst&127)<<17 | src. All atomics LDS; global writes coalesced.
// ---------------------------------------------------------------------------
__global__ __launch_bounds__(256) void k_binsort(const int* __restrict__ src,
                                                 const int* __restrict__ dst,
                                                 int* __restrict__ codes,
                                                 int* __restrict__ base) {
    __shared__ int hist[NBUCK];
    __shared__ int scan[256];
    __shared__ int lcode[SLICE];    // 32 KB staging
    const int blk = blockIdx.x;
    const int t   = threadIdx.x;

    for (int i = t; i < NBUCK; i += 256) hist[i] = 0;
    __syncthreads();

    const int4* d4 = reinterpret_cast<const int4*>(dst) + blk * (SLICE / 4);
    const int4* s4 = reinterpret_cast<const int4*>(src) + blk * (SLICE / 4);

    for (int k = t; k < SLICE / 4; k += 256) {
        const int4 d = d4[k];
        atomicAdd(&hist[d.x >> 7], 1);
        atomicAdd(&hist[d.y >> 7], 1);
        atomicAdd(&hist[d.z >> 7], 1);
        atomicAdd(&hist[d.w >> 7], 1);
    }
    __syncthreads();

    const int v0 = hist[4 * t], v1 = hist[4 * t + 1],
              v2 = hist[4 * t + 2], v3 = hist[4 * t + 3];
    const int tsum = v0 + v1 + v2 + v3;
    scan[t] = tsum;
    __syncthreads();
    for (int off = 1; off < 256; off <<= 1) {
        const int x = (t >= off) ? scan[t - off] : 0;
        __syncthreads();
        scan[t] += x;
        __syncthreads();
    }
    const int excl = scan[t] - tsum;
    const int e0 = excl, e1 = e0 + v0, e2 = e1 + v1, e3 = e2 + v2;
    hist[4 * t]     = e0;
    hist[4 * t + 1] = e1;
    hist[4 * t + 2] = e2;
    hist[4 * t + 3] = e3;
    int4 eb; eb.x = e0; eb.y = e1; eb.z = e2; eb.w = e3;
    reinterpret_cast<int4*>(base + (size_t)blk * NBUCK)[t] = eb;
    __syncthreads();

    for (int k = t; k < SLICE / 4; k += 256) {
        const int4 d = d4[k];
        const int4 s = s4[k];
        int p;
        p = atomicAdd(&hist[d.x >> 7], 1); lcode[p] = ((d.x & 127) << 17) | s.x;
        p = atomicAdd(&hist[d.y >> 7], 1); lcode[p] = ((d.y & 127) << 17) | s.y;
        p = atomicAdd(&hist[d.z >> 7], 1); lcode[p] = ((d.z & 127) << 17) | s.z;
        p = atomicAdd(&hist[d.w >> 7], 1); lcode[p] = ((d.w & 127) << 17) | s.w;
    }
    __syncthreads();

    int4* out4 = reinterpret_cast<int4*>(codes) + blk * (SLICE / 4);
    for (int k = t; k < SLICE / 4; k += 256)
        out4[k] = reinterpret_cast<const int4*>(lcode)[k];
}

// ---------------------------------------------------------------------------
// Pass 3: in-degree per node from sorted codes (LDS accumulate, 1 blk/bucket)
// ---------------------------------------------------------------------------
__global__ __launch_bounds__(256) void k_deg2(const int* __restrict__ codes,
                                              const int* __restrict__ base,
                                              int* __restrict__ deg) {
    __shared__ int acc[BNODES];
    const int b = blockIdx.x;
    const int t = threadIdx.x;
    if (t < BNODES) acc[t] = 0;
    __syncthreads();
    const int s0 = base[(size_t)t * NBUCK + b];
    const int s1 = (b == NBUCK - 1) ? SLICE : base[(size_t)t * NBUCK + b + 1];
    const int* c = codes + (size_t)t * SLICE;
    for (int k = s0; k < s1; ++k) atomicAdd(&acc[c[k] >> 17], 1);
    __syncthreads();
    if (t < BNODES) deg[b * BNODES + t] = acc[t];
}

// dinv = (deg+1)^-0.5 ; g = h * dinv  (source-side weight)
__global__ __launch_bounds__(256) void k_prep(const int* __restrict__ deg,
                                              const float* __restrict__ h,
                                              float* __restrict__ dinv,
                                              float* __restrict__ g) {
    const int i = blockIdx.x * blockDim.x + threadIdx.x;
    const float di = 1.0f / sqrtf((float)(deg[i] + 1)); // +1: self loop
    dinv[i] = di;
    g[i] = h[i] * di;
}

// ---------------------------------------------------------------------------
// Pass 4: attn accumulate (LDS) + fused finalize.
// ---------------------------------------------------------------------------
__global__ __launch_bounds__(256) void k_attn(const int* __restrict__ codes,
                                              const int* __restrict__ base,
                                              const float* __restrict__ g,
                                              const float* __restrict__ dinv,
                                              const float* __restrict__ bias,
                                              float* __restrict__ attn) {
    __shared__ float acc[BNODES];
    const int b = blockIdx.x;
    const int t = threadIdx.x;
    if (t < BNODES) acc[t] = 0.0f;
    __syncthreads();
    const int s0 = base[(size_t)t * NBUCK + b];
    const int s1 = (b == NBUCK - 1) ? SLICE : base[(size_t)t * NBUCK + b + 1];
    const int* c = codes + (size_t)t * SLICE;
    for (int k = s0; k < s1; ++k) {
        const int code = c[k];
        atomicAdd(&acc[code >> 17], g[code & 0x1FFFF]);
    }
    __syncthreads();
    if (t < BNODES) {
        const int node = b * BNODES + t;
        attn[node] = (acc[t] + g[node]) * dinv[node] + bias[0];
    }
}

// ---------------------------------------------------------------------------
// Pass 5: exact top-k by rank with composite 64-bit keys.
// K_i = (mono(score_i) << 11) | (2047 - i_local); all K distinct.
// rank(i) = #{j: K_j > K_i}  ==  reference descending-score, index tie-break.
// Block = 256 thr (4 waves), owns 512 i's (quarter graph); each wave scans a
// 512-j chunk for ALL 512 i's (8 i-keys/lane), partial counts combined in LDS.
// ---------------------------------------------------------------------------
__global__ __launch_bounds__(256) void k_topk(const float* __restrict__ attn,
                                              int* __restrict__ perm,
                                              int* __restrict__ newid) {
    __shared__ unsigned long long key[NPG];   // 16 KB
    __shared__ int pc[4][512];                // 8 KB partial counts
    const int g = blockIdx.x >> 2;            // graph
    const int q = blockIdx.x & 3;             // quarter (i-range)
    const int t = threadIdx.x;
    const int wave = t >> 6;
    const int lane = t & 63;

    // Build keys for the whole graph (coalesced float4 loads)
    const float4* a4 = reinterpret_cast<const float4*>(attn + (size_t)g * NPG);
    for (int k4 = t; k4 < NPG / 4; k4 += 256) {
        const float4 v = a4[k4];
        const int j = k4 * 4;
        #pragma unroll
        for (int e = 0; e < 4; ++e) {
            const float f = (e == 0) ? v.x : (e == 1) ? v.y : (e == 2) ? v.z : v.w;
            unsigned int u = __float_as_uint(f);
            unsigned int m = (u & 0x80000000u) ? ~u : (u | 0x80000000u); // monotone
            key[j + e] = ((unsigned long long)m << 11) | (unsigned)(NPG - 1 - (j + e));
        }
    }
    __syncthreads();

    // Each lane holds 8 i-keys of the block's 512-i range
    unsigned long long ki[8];
    int c[8];
    #pragma unroll
    for (int r = 0; r < 8; ++r) {
        ki[r] = key[q * 512 + r * 64 + lane];
        c[r] = 0;
    }

    // Wave scans its own 512-j chunk (broadcast reads, conflict-free)
    const ulonglong2* k2 = reinterpret_cast<const ulonglong2*>(key) + wave * 256;
    #pragma unroll 4
    for (int k = 0; k < 256; ++k) {
        const ulonglong2 kk = k2[k];
        #pragma unroll
        for (int r = 0; r < 8; ++r) {
            c[r] += (int)(kk.x > ki[r]);
            c[r] += (int)(kk.y > ki[r]);
        }
    }
    #pragma unroll
    for (int r = 0; r < 8; ++r) pc[wave][r * 64 + lane] = c[r];
    __syncthreads();

    // Combine partials; thread t outputs i_local = t and t+256
    #pragma unroll
    for (int e = 0; e < 2; ++e) {
        const int il = e * 256 + t;
        const int rank = pc[0][il] + pc[1][il] + pc[2][il] + pc[3][il];
        const int node = g * NPG + q * 512 + il;
        if (rank < KKEEP) {
            const int id = g * KKEEP + rank;
            perm[id] = node;
            newid[node] = id;
        } else {
            newid[node] = -1;
        }
    }
}

// ---------------------------------------------------------------------------
// Pass 6: gather kept rows, gate by tanh(score); graph indicator = row/K
// ---------------------------------------------------------------------------
__global__ __launch_bounds__(256) void k_gather(const float* __restrict__ X,
                                                const float* __restrict__ attn,
                                                const int* __restrict__ perm,
                                                float* __restrict__ out_x,
                                                float* __restrict__ out_gi) {
    const int wave = threadIdx.x >> 6;
    const int lane = threadIdx.x & 63;
    const int row  = blockIdx.x * 4 + wave;
    const int node = perm[row];
    const float gate = tanhf(attn[node]);
    const float4 x = *reinterpret_cast<const float4*>(X + (size_t)node * DFEAT + lane * 4);
    float4 o;
    o.x = x.x * gate; o.y = x.y * gate; o.z = x.z * gate; o.w = x.w * gate;
    *reinterpret_cast<float4*>(out_x + (size_t)row * DFEAT + lane * 4) = o;
    if (lane == 0) out_gi[row] = (float)(row >> 10);   // row / KKEEP
}

// ---------------------------------------------------------------------------
// Pass 7: edge remap; dropped edges -> -1
// ---------------------------------------------------------------------------
__global__ __launch_bounds__(256) void k_edges(const int* __restrict__ src,
                                               const int* __restrict__ dst,
                                               const int* __restrict__ newid,
                                               float* __restrict__ out_src,
                                               float* __restrict__ out_dst) {
    const int i = blockIdx.x * blockDim.x + threadIdx.x;
    const int4 s = reinterpret_cast<const int4*>(src)[i];
    const int4 d = reinterpret_cast<const int4*>(dst)[i];
    const int ns0 = newid[s.x], nd0 = newid[d.x];
    const int ns1 = newid[s.y], nd1 = newid[d.y];
    const int ns2 = newid[s.z], nd2 = newid[d.z];
    const int ns3 = newid[s.w], nd3 = newid[d.w];
    float4 os, od;
    os.x = (ns0 >= 0 && nd0 >= 0) ? (float)ns0 : -1.0f;
    od.x = (ns0 >= 0 && nd0 >= 0) ? (float)nd0 : -1.0f;
    os.y = (ns1 >= 0 && nd1 >= 0) ? (float)ns1 : -1.0f;
    od.y = (ns1 >= 0 && nd1 >= 0) ? (float)nd1 : -1.0f;
    os.z = (ns2 >= 0 && nd2 >= 0) ? (float)ns2 : -1.0f;
    od.z = (ns2 >= 0 && nd2 >= 0) ? (float)nd2 : -1.0f;
    os.w = (ns3 >= 0 && nd3 >= 0) ? (float)ns3 : -1.0f;
    od.w = (ns3 >= 0 && nd3 >= 0) ? (float)nd3 : -1.0f;
    reinterpret_cast<float4*>(out_src)[i] = os;
    reinterpret_cast<float4*>(out_dst)[i] = od;
}

// ---------------------------------------------------------------------------
extern "C" void kernel_launch(void* const* d_in, const int* in_sizes, int n_in,
                              void* d_out, int out_size, void* d_ws, size_t ws_size,
                              hipStream_t stream) {
    const float* X  = (const float*)d_in[0];             // [N, 256]
    const int*   ei = (const int*)d_in[2];               // [2, E]
    const float* W  = (const float*)d_in[3];             // [256, 1]
    const float* b  = (const float*)d_in[4];             // [1]
    const int* src = ei;
    const int* dst = ei + NEDGES;

    // Workspace layout (everything fully written before read; no zeroing)
    char* ws = (char*)d_ws;
    int*   deg   = (int*)  (ws + 0 * (size_t)NNODES * 4);
    float* attn  = (float*)(ws + 1 * (size_t)NNODES * 4);
    float* h     = (float*)(ws + 2 * (size_t)NNODES * 4);
    float* dinv  = (float*)(ws + 3 * (size_t)NNODES * 4);
    float* gg    = (float*)(ws + 4 * (size_t)NNODES * 4);
    int*   newid = (int*)  (ws + 5 * (size_t)NNODES * 4);
    int*   perm  = (int*)  (ws + 6 * (size_t)NNODES * 4);

    // Output layout (all float32 values in one flat buffer)
    float* out_x   = (float*)d_out;                      // NKEPT*256
    float* out_src = out_x + (size_t)NKEPT * DFEAT;      // E
    float* out_dst = out_src + NEDGES;                   // E
    float* out_gi  = out_dst + NEDGES;                   // NKEPT

    // Binning scratch aliased into edge-output slots (consumed before k_edges)
    int* codes = (int*)out_src;                          // NEDGES ints
    int* base  = (int*)out_dst;                          // NBLK*NBUCK ints

    k_dot_rows<<<NNODES / 4, 256, 0, stream>>>(X, W, h);
    k_binsort <<<NBLK, 256, 0, stream>>>(src, dst, codes, base);
    k_deg2    <<<NBUCK, 256, 0, stream>>>(codes, base, deg);
    k_prep    <<<NNODES / 256, 256, 0, stream>>>(deg, h, dinv, gg);
    k_attn    <<<NBUCK, 256, 0, stream>>>(codes, base, gg, dinv, b, attn);
    k_topk    <<<NGRAPH * 4, 256, 0, stream>>>(attn, perm, newid);
    k_gather  <<<NKEPT / 4, 256, 0, stream>>>(X, attn, perm, out_x, out_gi);
    k_edges   <<<NEDGES / 4 / 256, 256, 0, stream>>>(src, dst, newid, out_src, out_dst);
}

// Round 7
// 332.817 us; speedup vs baseline: 1.8130x; 1.0296x over previous
//
#include <hip/hip_runtime.h>

// Problem constants (match reference file)
#define NPG     2048
#define KKEEP   1024
#define NNODES  131072
#define NEDGES  2097152
#define DFEAT   256
#define NGRAPH  64                 // NNODES / NPG
#define NKEPT   (NGRAPH * KKEEP)   // 65536

// Binning constants
#define NBLK    256                // edge slices (= threads per bucket-pass block)
#define SLICE   (NEDGES / NBLK)    // 8192 edges per slice
#define NBUCK   1024               // dst buckets (dst >> 7)
#define BNODES  (NNODES / NBUCK)   // 128 nodes per bucket

// Fused-launch geometry
#define DROWS   16                  // rows per dot block (4 rows per wave)
#define DOTBLKS (NNODES / DROWS)    // 8192
#define GROWS   16                  // rows per gather block
#define GATBLKS (NKEPT / GROWS)     // 4096
#define EDGBLKS (NEDGES / 4 / 256)  // 2048

// ---------------------------------------------------------------------------
// Stage 1 (fused launch): blocks [0,NBLK) = binsort edges by dst bucket;
// blocks [NBLK, NBLK+DOTBLKS) = h[i] = dot(X[i,:], W).
// Binsort blocks are latency-bound; dot blocks are BW-bound -> they overlap.
// code = (dst&127)<<17 | src. All binsort atomics in LDS; writes coalesced.
// ---------------------------------------------------------------------------
__global__ __launch_bounds__(256) void k_stage1(const float* __restrict__ X,
                                                const float* __restrict__ W,
                                                float* __restrict__ h,
                                                const int* __restrict__ src,
                                                const int* __restrict__ dst,
                                                int* __restrict__ codes,
                                                int* __restrict__ base) {
    __shared__ int hist[NBUCK];
    __shared__ int scanb[256];
    __shared__ int lcode[SLICE];    // 32 KB staging (38 KB total -> 4 blk/CU)
    const int t = threadIdx.x;

    if (blockIdx.x < NBLK) {
        // ---------------- binsort ----------------
        const int blk = blockIdx.x;
        for (int i = t; i < NBUCK; i += 256) hist[i] = 0;
        __syncthreads();

        const int4* d4 = reinterpret_cast<const int4*>(dst) + blk * (SLICE / 4);
        const int4* s4 = reinterpret_cast<const int4*>(src) + blk * (SLICE / 4);

        for (int k = t; k < SLICE / 4; k += 256) {
            const int4 d = d4[k];
            atomicAdd(&hist[d.x >> 7], 1);
            atomicAdd(&hist[d.y >> 7], 1);
            atomicAdd(&hist[d.z >> 7], 1);
            atomicAdd(&hist[d.w >> 7], 1);
        }
        __syncthreads();

        const int v0 = hist[4 * t], v1 = hist[4 * t + 1],
                  v2 = hist[4 * t + 2], v3 = hist[4 * t + 3];
        const int tsum = v0 + v1 + v2 + v3;
        scanb[t] = tsum;
        __syncthreads();
        for (int off = 1; off < 256; off <<= 1) {
            const int x = (t >= off) ? scanb[t - off] : 0;
            __syncthreads();
            scanb[t] += x;
            __syncthreads();
        }
        const int excl = scanb[t] - tsum;
        const int e0 = excl, e1 = e0 + v0, e2 = e1 + v1, e3 = e2 + v2;
        hist[4 * t]     = e0;
        hist[4 * t + 1] = e1;
        hist[4 * t + 2] = e2;
        hist[4 * t + 3] = e3;
        int4 eb; eb.x = e0; eb.y = e1; eb.z = e2; eb.w = e3;
        reinterpret_cast<int4*>(base + (size_t)blk * NBUCK)[t] = eb;
        __syncthreads();

        for (int k = t; k < SLICE / 4; k += 256) {
            const int4 d = d4[k];
            const int4 s = s4[k];
            int p;
            p = atomicAdd(&hist[d.x >> 7], 1); lcode[p] = ((d.x & 127) << 17) | s.x;
            p = atomicAdd(&hist[d.y >> 7], 1); lcode[p] = ((d.y & 127) << 17) | s.y;
            p = atomicAdd(&hist[d.z >> 7], 1); lcode[p] = ((d.z & 127) << 17) | s.z;
            p = atomicAdd(&hist[d.w >> 7], 1); lcode[p] = ((d.w & 127) << 17) | s.w;
        }
        __syncthreads();

        int4* out4 = reinterpret_cast<int4*>(codes) + blk * (SLICE / 4);
        for (int k = t; k < SLICE / 4; k += 256)
            out4[k] = reinterpret_cast<const int4*>(lcode)[k];
    } else {
        // ---------------- dot rows ----------------
        const int bid  = blockIdx.x - NBLK;
        const int wave = t >> 6;
        const int lane = t & 63;
        const float4 w = *reinterpret_cast<const float4*>(W + lane * 4);
        const int row0 = bid * DROWS + wave * (DROWS / 4);
        #pragma unroll
        for (int r = 0; r < DROWS / 4; ++r) {
            const int row = row0 + r;
            const float4 x = *reinterpret_cast<const float4*>(X + (size_t)row * DFEAT + lane * 4);
            float v = x.x * w.x + x.y * w.y + x.z * w.z + x.w * w.w;
            #pragma unroll
            for (int off = 32; off; off >>= 1) v += __shfl_down(v, off, 64);
            if (lane == 0) h[row] = v;
        }
    }
}

// ---------------------------------------------------------------------------
// Stage 2: degree (LDS accumulate from sorted codes) fused with prep:
// block b owns nodes [b*128, b*128+128): dinv = (deg+1)^-0.5, g = h*dinv.
// ---------------------------------------------------------------------------
__global__ __launch_bounds__(256) void k_degprep(const int* __restrict__ codes,
                                                 const int* __restrict__ base,
                                                 const float* __restrict__ h,
                                                 float* __restrict__ dinv,
                                                 float* __restrict__ g) {
    __shared__ int acc[BNODES];
    const int b = blockIdx.x;
    const int t = threadIdx.x;
    if (t < BNODES) acc[t] = 0;
    __syncthreads();
    const int s0 = base[(size_t)t * NBUCK + b];
    const int s1 = (b == NBUCK - 1) ? SLICE : base[(size_t)t * NBUCK + b + 1];
    const int* c = codes + (size_t)t * SLICE;
    for (int k = s0; k < s1; ++k) atomicAdd(&acc[c[k] >> 17], 1);
    __syncthreads();
    if (t < BNODES) {
        const int node = b * BNODES + t;
        const float di = 1.0f / sqrtf((float)(acc[t] + 1)); // +1: self loop
        dinv[node] = di;
        g[node] = h[node] * di;
    }
}

// ---------------------------------------------------------------------------
// Stage 3: attn accumulate (LDS) + fused finalize.
// attn[n] = (sum_{edges s->n} g[s] + g[n]) * dinv[n] + bias
// ---------------------------------------------------------------------------
__global__ __launch_bounds__(256) void k_attn(const int* __restrict__ codes,
                                              const int* __restrict__ base,
                                              const float* __restrict__ g,
                                              const float* __restrict__ dinv,
                                              const float* __restrict__ bias,
                                              float* __restrict__ attn) {
    __shared__ float acc[BNODES];
    const int b = blockIdx.x;
    const int t = threadIdx.x;
    if (t < BNODES) acc[t] = 0.0f;
    __syncthreads();
    const int s0 = base[(size_t)t * NBUCK + b];
    const int s1 = (b == NBUCK - 1) ? SLICE : base[(size_t)t * NBUCK + b + 1];
    const int* c = codes + (size_t)t * SLICE;
    for (int k = s0; k < s1; ++k) {
        const int code = c[k];
        atomicAdd(&acc[code >> 17], g[code & 0x1FFFF]);
    }
    __syncthreads();
    if (t < BNODES) {
        const int node = b * BNODES + t;
        attn[node] = (acc[t] + g[node]) * dinv[node] + bias[0];
    }
}

// ---------------------------------------------------------------------------
// Stage 4: exact top-k by rank with composite 64-bit keys.
// K_i = (mono(score_i) << 11) | (2047 - i_local); all K distinct.
// rank(i) = #{j: K_j > K_i}  ==  reference descending-score, index tie-break.
// 4 blocks/graph; each wave scans a 512-j chunk for all 512 i's.
// ---------------------------------------------------------------------------
__global__ __launch_bounds__(256) void k_topk(const float* __restrict__ attn,
                                              int* __restrict__ perm,
                                              int* __restrict__ newid) {
    __shared__ unsigned long long key[NPG];   // 16 KB
    __shared__ int pc[4][512];                // 8 KB partial counts
    const int g = blockIdx.x >> 2;            // graph
    const int q = blockIdx.x & 3;             // quarter (i-range)
    const int t = threadIdx.x;
    const int wave = t >> 6;
    const int lane = t & 63;

    const float4* a4 = reinterpret_cast<const float4*>(attn + (size_t)g * NPG);
    for (int k4 = t; k4 < NPG / 4; k4 += 256) {
        const float4 v = a4[k4];
        const int j = k4 * 4;
        #pragma unroll
        for (int e = 0; e < 4; ++e) {
            const float f = (e == 0) ? v.x : (e == 1) ? v.y : (e == 2) ? v.z : v.w;
            unsigned int u = __float_as_uint(f);
            unsigned int m = (u & 0x80000000u) ? ~u : (u | 0x80000000u); // monotone
            key[j + e] = ((unsigned long long)m << 11) | (unsigned)(NPG - 1 - (j + e));
        }
    }
    __syncthreads();

    unsigned long long ki[8];
    int c[8];
    #pragma unroll
    for (int r = 0; r < 8; ++r) {
        ki[r] = key[q * 512 + r * 64 + lane];
        c[r] = 0;
    }

    const ulonglong2* k2 = reinterpret_cast<const ulonglong2*>(key) + wave * 256;
    #pragma unroll 4
    for (int k = 0; k < 256; ++k) {
        const ulonglong2 kk = k2[k];
        #pragma unroll
        for (int r = 0; r < 8; ++r) {
            c[r] += (int)(kk.x > ki[r]);
            c[r] += (int)(kk.y > ki[r]);
        }
    }
    #pragma unroll
    for (int r = 0; r < 8; ++r) pc[wave][r * 64 + lane] = c[r];
    __syncthreads();

    #pragma unroll
    for (int e = 0; e < 2; ++e) {
        const int il = e * 256 + t;
        const int rank = pc[0][il] + pc[1][il] + pc[2][il] + pc[3][il];
        const int node = g * NPG + q * 512 + il;
        if (rank < KKEEP) {
            const int id = g * KKEEP + rank;
            perm[id] = node;
            newid[node] = id;
        } else {
            newid[node] = -1;
        }
    }
}

// ---------------------------------------------------------------------------
// Stage 5 (fused launch): blocks [0,EDGBLKS) = edge remap (-1 for dropped);
// blocks [EDGBLKS, EDGBLKS+GATBLKS) = gather kept rows gated by tanh(score).
// Edge blocks are gather-latency-bound; gather blocks are BW-bound -> overlap.
// ---------------------------------------------------------------------------
__global__ __launch_bounds__(256) void k_stage5(const float* __restrict__ X,
                                                const float* __restrict__ attn,
                                                const int* __restrict__ perm,
                                                const int* __restrict__ newid,
                                                const int* __restrict__ src,
                                                const int* __restrict__ dst,
                                                float* __restrict__ out_x,
                                                float* __restrict__ out_gi,
                                                float* __restrict__ out_src,
                                                float* __restrict__ out_dst) {
    if (blockIdx.x < EDGBLKS) {
        // ---------------- edge remap ----------------
        const int i = blockIdx.x * 256 + threadIdx.x;
        const int4 s = reinterpret_cast<const int4*>(src)[i];
        const int4 d = reinterpret_cast<const int4*>(dst)[i];
        const int ns0 = newid[s.x], nd0 = newid[d.x];
        const int ns1 = newid[s.y], nd1 = newid[d.y];
        const int ns2 = newid[s.z], nd2 = newid[d.z];
        const int ns3 = newid[s.w], nd3 = newid[d.w];
        float4 os, od;
        os.x = (ns0 >= 0 && nd0 >= 0) ? (float)ns0 : -1.0f;
        od.x = (ns0 >= 0 && nd0 >= 0) ? (float)nd0 : -1.0f;
        os.y = (ns1 >= 0 && nd1 >= 0) ? (float)ns1 : -1.0f;
        od.y = (ns1 >= 0 && nd1 >= 0) ? (float)nd1 : -1.0f;
        os.z = (ns2 >= 0 && nd2 >= 0) ? (float)ns2 : -1.0f;
        od.z = (ns2 >= 0 && nd2 >= 0) ? (float)nd2 : -1.0f;
        os.w = (ns3 >= 0 && nd3 >= 0) ? (float)ns3 : -1.0f;
        od.w = (ns3 >= 0 && nd3 >= 0) ? (float)nd3 : -1.0f;
        reinterpret_cast<float4*>(out_src)[i] = os;
        reinterpret_cast<float4*>(out_dst)[i] = od;
    } else {
        // ---------------- gather + gate ----------------
        const int bid  = blockIdx.x - EDGBLKS;
        const int wave = threadIdx.x >> 6;
        const int lane = threadIdx.x & 63;
        const int row0 = bid * GROWS + wave * (GROWS / 4);
        #pragma unroll
        for (int r = 0; r < GROWS / 4; ++r) {
            const int row  = row0 + r;
            const int node = perm[row];
            const float gate = tanhf(attn[node]);
            const float4 x = *reinterpret_cast<const float4*>(X + (size_t)node * DFEAT + lane * 4);
            float4 o;
            o.x = x.x * gate; o.y = x.y * gate; o.z = x.z * gate; o.w = x.w * gate;
            *reinterpret_cast<float4*>(out_x + (size_t)row * DFEAT + lane * 4) = o;
            if (lane == 0) out_gi[row] = (float)(row >> 10);   // row / KKEEP
        }
    }
}

// ---------------------------------------------------------------------------
extern "C" void kernel_launch(void* const* d_in, const int* in_sizes, int n_in,
                              void* d_out, int out_size, void* d_ws, size_t ws_size,
                              hipStream_t stream) {
    const float* X  = (const float*)d_in[0];             // [N, 256]
    const int*   ei = (const int*)d_in[2];               // [2, E]
    const float* W  = (const float*)d_in[3];             // [256, 1]
    const float* b  = (const float*)d_in[4];             // [1]
    const int* src = ei;
    const int* dst = ei + NEDGES;

    // Workspace layout (everything fully written before read; no zeroing)
    char* ws = (char*)d_ws;
    float* attn  = (float*)(ws + 0 * (size_t)NNODES * 4);
    float* h     = (float*)(ws + 1 * (size_t)NNODES * 4);
    float* dinv  = (float*)(ws + 2 * (size_t)NNODES * 4);
    float* gg    = (float*)(ws + 3 * (size_t)NNODES * 4);
    int*   newid = (int*)  (ws + 4 * (size_t)NNODES * 4);
    int*   perm  = (int*)  (ws + 5 * (size_t)NNODES * 4);

    // Output layout (all float32 values in one flat buffer)
    float* out_x   = (float*)d_out;                      // NKEPT*256
    float* out_src = out_x + (size_t)NKEPT * DFEAT;      // E
    float* out_dst = out_src + NEDGES;                   // E
    float* out_gi  = out_dst + NEDGES;                   // NKEPT

    // Binning scratch aliased into edge-output slots (consumed by stages 2-3,
    // overwritten only by stage 5)
    int* codes = (int*)out_src;                          // NEDGES ints
    int* base  = (int*)out_dst;                          // NBLK*NBUCK ints

    k_stage1 <<<NBLK + DOTBLKS, 256, 0, stream>>>(X, W, h, src, dst, codes, base);
    k_degprep<<<NBUCK, 256, 0, stream>>>(codes, base, h, dinv, gg);
    k_attn   <<<NBUCK, 256, 0, stream>>>(codes, base, gg, dinv, b, attn);
    k_topk   <<<NGRAPH * 4, 256, 0, stream>>>(attn, perm, newid);
    k_stage5 <<<EDGBLKS + GATBLKS, 256, 0, stream>>>(X, attn, perm, newid, src, dst,
                                                     out_x, out_gi, out_src, out_dst);
}